// Round 7
// baseline (1490.348 us; speedup 1.0000x reference)
//
#include <hip/hip_runtime.h>
#include <hip/hip_bf16.h>

#define NROW 16384
#define DIM 128
#define HOUT 256
#define SPLIT 4

typedef float f32x4 __attribute__((ext_vector_type(4)));
typedef __bf16 bf16x8 __attribute__((ext_vector_type(8)));
typedef int v4i __attribute__((ext_vector_type(4)));
typedef unsigned int u32;
typedef unsigned int u32x4 __attribute__((ext_vector_type(4)));

// ---------------- Kernel 1: features f32 [N][128] -> fT bf16 [128][N]; zero deg ----
__global__ void k_transpose(const float* __restrict__ f, short* __restrict__ fT,
                            float* __restrict__ deg) {
    __shared__ short tr[128][72];
    const int t = threadIdx.x;
    const int j0 = blockIdx.x * 64;
    if (blockIdx.x < 64) deg[blockIdx.x * 256 + t] = 0.f;   // zero 16384 floats
    for (int it = 0; it < 8; ++it) {
        int slot = t + 256 * it;
        int j = slot >> 5;          // 0..63
        int dq = slot & 31;         // d = dq*4
        f32x4 v = *reinterpret_cast<const f32x4*>(f + (size_t)(j0 + j) * DIM + dq * 4);
#pragma unroll
        for (int c = 0; c < 4; ++c) {
            __hip_bfloat16 h = __float2bfloat16(v[c]);
            tr[dq * 4 + c][j] = *reinterpret_cast<short*>(&h);
        }
    }
    __syncthreads();
    for (int it = 0; it < 4; ++it) {
        int slot = t + 256 * it;
        int d = slot >> 3;          // 0..127
        int c8 = slot & 7;          // 8-bf16 chunk
        int4 v = *reinterpret_cast<const int4*>(&tr[d][c8 * 8]);
        *reinterpret_cast<int4*>(fT + (size_t)d * NROW + j0 + c8 * 8) = v;
    }
}

// ---------------- Kernel 2: gload_lds GEMM, K_STEP=64, XOR-swizzled LDS -------------
// R6 + two changes: (1) K_STEP 32->64 (256B per adj row per step: longer DRAM touches,
// half the barriers), (2) T2 bank-conflict fix via the rule-#21 involution: LDS dest
// stays LINEAR (gload_lds requirement), the global SOURCE column-chunk is permuted
// (c ^ (row&7)), and the READ byte offset applies the same XOR ((lr&7)<<4).
// Block: 64 rows x 128 d, 4 waves (wave = 16 rows x 128 d, acc = 32 VGPR).
// Grid: 256 row-blocks x SPLIT(4) = 1024, LDS 64 KB -> 2 blocks/CU.
// Fragment layouts (verified passing R1-R6):
//   A (16x32): lane holds row (lane&15), k = (lane>>4)*8 .. +8
//   B (32x16): lane holds col (lane&15), k = (lane>>4)*8 .. +8
//   C (16x16): col = lane&15, row = (lane>>4)*4 + r
__device__ inline bf16x8 cvt8(v4i a, v4i b, int& ds) {
    union { u32x4 u; bf16x8 f; } U;
    U.u[0] = (a[0] ? 0x3F80u : 0u) | (a[1] ? 0x3F800000u : 0u);
    U.u[1] = (a[2] ? 0x3F80u : 0u) | (a[3] ? 0x3F800000u : 0u);
    U.u[2] = (b[0] ? 0x3F80u : 0u) | (b[1] ? 0x3F800000u : 0u);
    U.u[3] = (b[2] ? 0x3F80u : 0u) | (b[3] ? 0x3F800000u : 0u);
    ds += a[0] + a[1] + a[2] + a[3] + b[0] + b[1] + b[2] + b[3];
    return U.f;
}

#define GLOAD16(g, l)                                                         \
    __builtin_amdgcn_global_load_lds(                                         \
        (const __attribute__((address_space(1))) unsigned int*)(g),           \
        (__attribute__((address_space(3))) unsigned int*)(l), 16, 0, 0)

__global__ __launch_bounds__(256, 2) void k_gemm(const int* __restrict__ adj,
                                                 const short* __restrict__ fT,
                                                 float* __restrict__ part,
                                                 float* __restrict__ deg) {
    __shared__ int   As[2][64][64];    // 2 x 16 KB, row = 256 B
    __shared__ short Fs[2][128][64];   // 2 x 16 KB, row = 128 B
    const int t = threadIdx.x;
    const int rb = blockIdx.x >> 2;          // 0..255: 64-row block
    const int s  = blockIdx.x & 3;           // K quarter
    const int i0 = rb * 64;
    const int kb0 = s * (NROW / SPLIT);      // 4096-wide K slice
    const int lane = t & 63;
    const int w = t >> 6;                    // wave id: rows w*16..+16
    const int lr = lane & 15;
    const int lk8 = lane >> 4;               // k-phase 0..3
    const int sw = (lr & 7) << 4;            // read-side XOR (matches source permute)

    f32x4 acc[8] = {};
    int dsum = 0;

    // Staging (linear LDS dest = slot*16; source column-chunk XOR-permuted):
    //  A: slot 0..1023: row=slot>>4, chunk c4=(slot&15)^(row&7); 16B each
    //  F: slot 0..1023: d=slot>>3,  chunk c8=(slot&7)^(d&7);    16B each
    // Lanes of a round cover a contiguous global region per row (permuted within it)
    // -> coalescing preserved.
#define STAGE(cur, kb)                                                             \
    do {                                                                           \
        _Pragma("unroll")                                                          \
        for (int r = 0; r < 4; ++r) {                                              \
            int uslot = r * 256 + w * 64;                                          \
            int slot = uslot + lane;                                               \
            int row = slot >> 4;                                                   \
            int c4 = (slot & 15) ^ (row & 7);                                      \
            GLOAD16(adj + (size_t)(i0 + row) * NROW + (kb) + c4 * 4,               \
                    (char*)&As[cur][0][0] + (size_t)uslot * 16);                   \
        }                                                                          \
        _Pragma("unroll")                                                          \
        for (int r = 0; r < 4; ++r) {                                              \
            int uslot = r * 256 + w * 64;                                          \
            int slot = uslot + lane;                                               \
            int d = slot >> 3;                                                     \
            int c8 = (slot & 7) ^ (d & 7);                                         \
            GLOAD16(fT + (size_t)d * NROW + (kb) + c8 * 8,                         \
                    (char*)&Fs[cur][0][0] + (size_t)uslot * 16);                   \
        }                                                                          \
    } while (0)

    STAGE(0, kb0);
    __syncthreads();                         // drains vmcnt (HIP barrier semantics)

    int cur = 0;
#pragma unroll 1
    for (int step = 0; step < 64; ++step) {  // 64 k-tiles of 64
        if (step + 1 < 64) STAGE(cur ^ 1, kb0 + (step + 1) * 64);
        const char* Ab = (const char*)&As[cur][0][0] + (w * 16 + lr) * 256;
        const char* Fb = (const char*)&Fs[cur][0][0];
#pragma unroll
        for (int kk = 0; kk < 2; ++kk) {     // two 32-k halves
            int xb = kk * 128 + lk8 * 32;    // A byte col (row-major, pre-swizzle)
            v4i a0 = *reinterpret_cast<const v4i*>(Ab + ((xb) ^ sw));
            v4i a1 = *reinterpret_cast<const v4i*>(Ab + ((xb + 16) ^ sw));
            bf16x8 af = cvt8(a0, a1, dsum);
            int cb = kk * 64 + lk8 * 16;     // F byte col
#pragma unroll
            for (int ci = 0; ci < 8; ++ci) {
                bf16x8 b = *reinterpret_cast<const bf16x8*>(
                    Fb + (ci * 16 + lr) * 128 + (cb ^ sw));
                acc[ci] = __builtin_amdgcn_mfma_f32_16x16x32_bf16(af, b, acc[ci], 0, 0, 0);
            }
        }
        __syncthreads();                     // next-tile loads landed; reads done
        cur ^= 1;
    }

    // store partials: C layout col=lane&15, row=(lane>>4)*4+r
#pragma unroll
    for (int ci = 0; ci < 8; ++ci)
#pragma unroll
        for (int r = 0; r < 4; ++r) {
            int i = i0 + w * 16 + (lane >> 4) * 4 + r;
            int d = ci * 16 + lr;
            part[((size_t)s * NROW + i) * DIM + d] = acc[ci][r];
        }
    // deg: lanes {lr, lr+16, lr+32, lr+48} hold k-phase sums of row w*16+lr
    {
        float v = (float)dsum;
        v += __shfl_xor(v, 16);
        v += __shfl_xor(v, 32);
        if (lane < 16) atomicAdd(deg + i0 + w * 16 + lr, v);
    }
#undef STAGE
}

// ---------------- Kernel 3: epilogue (unchanged) ------------------------------------
__global__ __launch_bounds__(256, 2) void k_epilogue(const float* __restrict__ feat,
                                                     const float* __restrict__ part,
                                                     const float* __restrict__ deg,
                                                     const float* __restrict__ Wd,
                                                     const float* __restrict__ bd,
                                                     const float* __restrict__ Wo,
                                                     const float* __restrict__ bo,
                                                     float* __restrict__ out) {
    __shared__ float fs[32][132];
    __shared__ float tn[32][132];
    __shared__ float mrow[32], inv[32];
    const int t = threadIdx.x;
    const int i0 = blockIdx.x * 32;
    if (t < 32) {
        float d = deg[i0 + t];
        mrow[t] = d > 0.f ? 1.f : 0.f;
        inv[t]  = d > 0.f ? 1.f / d : 1.f;
    }
    __syncthreads();
    for (int it = 0; it < 4; ++it) {
        int slot = t + 256 * it;
        int r = slot >> 5, dq = slot & 31;
        size_t gi = (size_t)(i0 + r) * DIM + dq * 4;
        f32x4 fv = *reinterpret_cast<const f32x4*>(feat + gi);
        *reinterpret_cast<f32x4*>(&fs[r][dq * 4]) = fv;
        f32x4 p = *reinterpret_cast<const f32x4*>(part + gi);
#pragma unroll
        for (int sp = 1; sp < SPLIT; ++sp)
            p += *reinterpret_cast<const f32x4*>(part + (size_t)sp * NROW * DIM + gi);
        f32x4 tv = p * inv[r];
        *reinterpret_cast<f32x4*>(&tn[r][dq * 4]) = tv;
    }
    __syncthreads();
    const int rt = t & 7;   // rows rt*4..+4
    const int ht = t >> 3;  // h = ht*8..+8
    float accM[4][8] = {};  // f·Wo − tn·Wd2
    float accB[4][8] = {};  // f·Wd1
    for (int d = 0; d < DIM; d += 4) {
        f32x4 fr[4], tr[4];
#pragma unroll
        for (int rr = 0; rr < 4; ++rr) {
            fr[rr] = *reinterpret_cast<const f32x4*>(&fs[rt * 4 + rr][d]);
            tr[rr] = *reinterpret_cast<const f32x4*>(&tn[rt * 4 + rr][d]);
        }
#pragma unroll
        for (int hh = 0; hh < 8; ++hh) {
            int h = ht * 8 + hh;
            f32x4 wo = *reinterpret_cast<const f32x4*>(Wo + (size_t)h * DIM + d);
            f32x4 w1 = *reinterpret_cast<const f32x4*>(Wd + (size_t)h * 2 * DIM + d);
            f32x4 w2 = *reinterpret_cast<const f32x4*>(Wd + (size_t)h * 2 * DIM + DIM + d);
#pragma unroll
            for (int rr = 0; rr < 4; ++rr)
#pragma unroll
                for (int c = 0; c < 4; ++c) {
                    accM[rr][hh] += fr[rr][c] * wo[c] - tr[rr][c] * w2[c];
                    accB[rr][hh] += fr[rr][c] * w1[c];
                }
        }
    }
    f32x4 bo0 = *reinterpret_cast<const f32x4*>(bo + ht * 8);
    f32x4 bo1 = *reinterpret_cast<const f32x4*>(bo + ht * 8 + 4);
    f32x4 bd0 = *reinterpret_cast<const f32x4*>(bd + ht * 8);
    f32x4 bd1 = *reinterpret_cast<const f32x4*>(bd + ht * 8 + 4);
#pragma unroll
    for (int rr = 0; rr < 4; ++rr) {
        int i = i0 + rt * 4 + rr;
        float m = mrow[rt * 4 + rr];
        f32x4 v0, v1;
#pragma unroll
        for (int c = 0; c < 4; ++c) {
            v0[c] = tanhf(accM[rr][c]     - m * accB[rr][c]     + bo0[c] - bd0[c]);
            v1[c] = tanhf(accM[rr][c + 4] - m * accB[rr][c + 4] + bo1[c] - bd1[c]);
        }
        float* o = out + (size_t)i * HOUT + ht * 8;
        *reinterpret_cast<f32x4*>(o) = v0;
        *reinterpret_cast<f32x4*>(o + 4) = v1;
        float* o2 = o + (size_t)NROW * HOUT;
        *reinterpret_cast<f32x4*>(o2) = v0;
        *reinterpret_cast<f32x4*>(o2 + 4) = v1;
    }
}

extern "C" void kernel_launch(void* const* d_in, const int* in_sizes, int n_in,
                              void* d_out, int out_size, void* d_ws, size_t ws_size,
                              hipStream_t stream) {
    const float* feat = (const float*)d_in[0];
    const int*   adj  = (const int*)d_in[1];
    const float* Wd   = (const float*)d_in[2];
    const float* bd   = (const float*)d_in[3];
    const float* Wo   = (const float*)d_in[4];
    const float* bo   = (const float*)d_in[5];
    float* out = (float*)d_out;
    char* ws = (char*)d_ws;
    short* fT   = (short*)ws;                              //  4 MB: [128][16384] bf16
    float* part = (float*)(ws + (size_t)4  * 1024 * 1024); // 33.5 MB: [4][16384][128] f32
    float* deg  = (float*)(ws + (size_t)40 * 1024 * 1024); // 64 KB
    k_transpose<<<256,  256, 0, stream>>>(feat, fT, deg);
    k_gemm     <<<1024, 256, 0, stream>>>(adj, fT, part, deg);
    k_epilogue <<<512,  256, 0, stream>>>(feat, part, deg, Wd, bd, Wo, bo, out);
}

// Round 9
// 1427.368 us; speedup vs baseline: 1.0441x; 1.0441x over previous
//
#include <hip/hip_runtime.h>
#include <hip/hip_bf16.h>

#define NROW 16384
#define DIM 128
#define HOUT 256
#define SPLIT 4

typedef float f32x4 __attribute__((ext_vector_type(4)));
typedef __bf16 bf16x8 __attribute__((ext_vector_type(8)));
typedef int v4i __attribute__((ext_vector_type(4)));
typedef unsigned int u32;
typedef unsigned int u32x4 __attribute__((ext_vector_type(4)));

// ---------------- Kernel 1: features f32 [N][128] -> fT bf16 [128][N]; zero deg ----
__global__ void k_transpose(const float* __restrict__ f, short* __restrict__ fT,
                            float* __restrict__ deg) {
    __shared__ short tr[128][72];
    const int t = threadIdx.x;
    const int j0 = blockIdx.x * 64;
    if (blockIdx.x < 64) deg[blockIdx.x * 256 + t] = 0.f;   // zero 16384 floats
    for (int it = 0; it < 8; ++it) {
        int slot = t + 256 * it;
        int j = slot >> 5;          // 0..63
        int dq = slot & 31;         // d = dq*4
        f32x4 v = *reinterpret_cast<const f32x4*>(f + (size_t)(j0 + j) * DIM + dq * 4);
#pragma unroll
        for (int c = 0; c < 4; ++c) {
            __hip_bfloat16 h = __float2bfloat16(v[c]);
            tr[dq * 4 + c][j] = *reinterpret_cast<short*>(&h);
        }
    }
    __syncthreads();
    for (int it = 0; it < 4; ++it) {
        int slot = t + 256 * it;
        int d = slot >> 3;          // 0..127
        int c8 = slot & 7;          // 8-bf16 chunk
        int4 v = *reinterpret_cast<const int4*>(&tr[d][c8 * 8]);
        *reinterpret_cast<int4*>(fT + (size_t)d * NROW + j0 + c8 * 8) = v;
    }
}

// ---------------- Kernel 2: R6 structure + counted-vmcnt 2-phase pipeline -----------
// Block: 128 rows x 128 d x K_STEP=32, double-buffered LDS (48 KB), 4 waves.
// Each wave issues exactly 6 gload_lds per tile (A:4 + F:2). Loop per step:
//   [ds_read + cvt + 16 MFMA on buf]  -> lgkmcnt(0), s_barrier   (reads of buf done)
//   STAGE(tile step+2 -> buf)         -> s_waitcnt vmcnt(6)      (tile step+1 landed;
//                                        step+2's 6 loads stay in flight across the
//                                        barrier and the whole next compute phase)
//   s_barrier
// vmcnt never drains to 0 in-loop (T3-lite/T4; m218). sched_barrier(0) fences per
// rule #18. Grid: 128 row-blocks x SPLIT(4) = 512 = 2 blocks/CU; s = bid&3 keeps one
// K-quarter fT slice per XCD (bid%8 -> s const per XCD).
// Fragment layouts (verified passing R1-R7):
//   A (16x32): lane holds row (lane&15), k = (lane>>4)*8 .. +8
//   B (32x16): lane holds col (lane&15), k = (lane>>4)*8 .. +8
//   C (16x16): col = lane&15, row = (lane>>4)*4 + r
__device__ inline bf16x8 cvt8(v4i a, v4i b, int& ds) {
    union { u32x4 u; bf16x8 f; } U;
    U.u[0] = (a[0] ? 0x3F80u : 0u) | (a[1] ? 0x3F800000u : 0u);
    U.u[1] = (a[2] ? 0x3F80u : 0u) | (a[3] ? 0x3F800000u : 0u);
    U.u[2] = (b[0] ? 0x3F80u : 0u) | (b[1] ? 0x3F800000u : 0u);
    U.u[3] = (b[2] ? 0x3F80u : 0u) | (b[3] ? 0x3F800000u : 0u);
    ds += a[0] + a[1] + a[2] + a[3] + b[0] + b[1] + b[2] + b[3];
    return U.f;
}

#define GLOAD16(g, l)                                                         \
    __builtin_amdgcn_global_load_lds(                                         \
        (const __attribute__((address_space(1))) unsigned int*)(g),           \
        (__attribute__((address_space(3))) unsigned int*)(l), 16, 0, 0)

#define SBAR()  __builtin_amdgcn_s_barrier()
#define SCHED() __builtin_amdgcn_sched_barrier(0)

__global__ __launch_bounds__(256, 2) void k_gemm(const int* __restrict__ adj,
                                                 const short* __restrict__ fT,
                                                 float* __restrict__ part,
                                                 float* __restrict__ deg) {
    __shared__ int   As[2][128][32];   // 2 x 16 KB
    __shared__ short Fs[2][128][32];   // 2 x  8 KB
    const int t = threadIdx.x;
    const int rb = blockIdx.x >> 2;          // 0..127: 128-row block
    const int s  = blockIdx.x & 3;           // K quarter (constant per XCD)
    const int i0 = rb * 128;
    const int kb0 = s * (NROW / SPLIT);      // 4096-wide K slice
    const int lane = t & 63;
    const int w = t >> 6;                    // wave id
    const int lr = lane & 15;
    const int lk8 = lane >> 4;               // k-phase 0..3

    f32x4 acc[2][8] = {};
    int dsum0 = 0, dsum1 = 0;

    // Staging (per wave: 4 A + 2 F = 6 gload_lds -> vmcnt counts 6 per tile):
    //  adj slots 0..1023 (row=slot>>3, kq=slot&7), LDS byte = slot*16
    //  fT  slots 0..511  (d=slot>>2,  c8=slot&3), LDS byte = slot*16
#define STAGE(cur, kb)                                                            \
    do {                                                                          \
        _Pragma("unroll")                                                         \
        for (int r = 0; r < 4; ++r) {                                             \
            int uslot = r * 256 + w * 64;                                         \
            int slot = uslot + lane;                                              \
            const int* g = adj + (size_t)(i0 + (slot >> 3)) * NROW + (kb) + (slot & 7) * 4; \
            GLOAD16(g, (char*)&As[cur][0][0] + (size_t)uslot * 16);               \
        }                                                                         \
        _Pragma("unroll")                                                         \
        for (int r = 0; r < 2; ++r) {                                             \
            int uslot = r * 256 + w * 64;                                         \
            int slot = uslot + lane;                                              \
            const short* g = fT + (size_t)(slot >> 2) * NROW + (kb) + (slot & 3) * 8; \
            GLOAD16(g, (char*)&Fs[cur][0][0] + (size_t)uslot * 16);               \
        }                                                                         \
    } while (0)

    STAGE(0, kb0);                       // tile 0 -> buf0 (6 loads)
    STAGE(1, kb0 + 32);                  // tile 1 -> buf1 (6 loads)
    asm volatile("s_waitcnt vmcnt(6)");  // tile 0 landed; tile 1 in flight
    SCHED(); SBAR(); SCHED();

#pragma unroll 1
    for (int step = 0; step < 128; ++step) {
        const int cur = step & 1;
        // consume tile `step` from buf `cur` (tile step+1 flying into buf cur^1)
        bf16x8 bfr[8];
#pragma unroll
        for (int ci = 0; ci < 8; ++ci)
            bfr[ci] = *reinterpret_cast<const bf16x8*>(&Fs[cur][ci * 16 + lr][lk8 * 8]);
        v4i a0 = *reinterpret_cast<const v4i*>(&As[cur][w * 32 + lr][lk8 * 8]);
        v4i a1 = *reinterpret_cast<const v4i*>(&As[cur][w * 32 + lr][lk8 * 8 + 4]);
        v4i a2 = *reinterpret_cast<const v4i*>(&As[cur][w * 32 + 16 + lr][lk8 * 8]);
        v4i a3 = *reinterpret_cast<const v4i*>(&As[cur][w * 32 + 16 + lr][lk8 * 8 + 4]);
        bf16x8 af0 = cvt8(a0, a1, dsum0);
        bf16x8 af1 = cvt8(a2, a3, dsum1);
#pragma unroll
        for (int ci = 0; ci < 8; ++ci) {
            acc[0][ci] = __builtin_amdgcn_mfma_f32_16x16x32_bf16(af0, bfr[ci], acc[0][ci], 0, 0, 0);
            acc[1][ci] = __builtin_amdgcn_mfma_f32_16x16x32_bf16(af1, bfr[ci], acc[1][ci], 0, 0, 0);
        }
        asm volatile("s_waitcnt lgkmcnt(0)");   // my reads of buf `cur` done
        SCHED();
        SBAR();                                  // everyone's reads of buf `cur` done
        SCHED();
        if (step + 2 < 128) {
            STAGE(cur, kb0 + (step + 2) * 32);   // overwrite buf `cur` with tile step+2
            asm volatile("s_waitcnt vmcnt(6)");  // tile step+1 certified; step+2 flying
        } else {
            asm volatile("s_waitcnt vmcnt(0)");  // tail: certify last tile
        }
        SCHED();
        SBAR();                                  // all waves agree: next tile ready
        SCHED();
    }

    // store partials: C layout col=lane&15, row=(lane>>4)*4+r
#pragma unroll
    for (int ti = 0; ti < 2; ++ti)
#pragma unroll
        for (int ci = 0; ci < 8; ++ci)
#pragma unroll
            for (int r = 0; r < 4; ++r) {
                int i = i0 + w * 32 + ti * 16 + (lane >> 4) * 4 + r;
                int d = ci * 16 + lr;
                part[((size_t)s * NROW + i) * DIM + d] = acc[ti][ci][r];
            }
    // deg: lanes {lr, lr+16, lr+32, lr+48} hold k-phase sums of rows (w*32+lr, +16)
    {
        float v0 = (float)dsum0;
        v0 += __shfl_xor(v0, 16);
        v0 += __shfl_xor(v0, 32);
        float v1 = (float)dsum1;
        v1 += __shfl_xor(v1, 16);
        v1 += __shfl_xor(v1, 32);
        if (lane < 16) {
            atomicAdd(deg + i0 + w * 32 + lr, v0);
            atomicAdd(deg + i0 + w * 32 + 16 + lr, v1);
        }
    }
#undef STAGE
}

// ---------------- Kernel 3: epilogue (unchanged) ------------------------------------
__global__ __launch_bounds__(256, 2) void k_epilogue(const float* __restrict__ feat,
                                                     const float* __restrict__ part,
                                                     const float* __restrict__ deg,
                                                     const float* __restrict__ Wd,
                                                     const float* __restrict__ bd,
                                                     const float* __restrict__ Wo,
                                                     const float* __restrict__ bo,
                                                     float* __restrict__ out) {
    __shared__ float fs[32][132];
    __shared__ float tn[32][132];
    __shared__ float mrow[32], inv[32];
    const int t = threadIdx.x;
    const int i0 = blockIdx.x * 32;
    if (t < 32) {
        float d = deg[i0 + t];
        mrow[t] = d > 0.f ? 1.f : 0.f;
        inv[t]  = d > 0.f ? 1.f / d : 1.f;
    }
    __syncthreads();
    for (int it = 0; it < 4; ++it) {
        int slot = t + 256 * it;
        int r = slot >> 5, dq = slot & 31;
        size_t gi = (size_t)(i0 + r) * DIM + dq * 4;
        f32x4 fv = *reinterpret_cast<const f32x4*>(feat + gi);
        *reinterpret_cast<f32x4*>(&fs[r][dq * 4]) = fv;
        f32x4 p = *reinterpret_cast<const f32x4*>(part + gi);
#pragma unroll
        for (int sp = 1; sp < SPLIT; ++sp)
            p += *reinterpret_cast<const f32x4*>(part + (size_t)sp * NROW * DIM + gi);
        f32x4 tv = p * inv[r];
        *reinterpret_cast<f32x4*>(&tn[r][dq * 4]) = tv;
    }
    __syncthreads();
    const int rt = t & 7;   // rows rt*4..+4
    const int ht = t >> 3;  // h = ht*8..+8
    float accM[4][8] = {};  // f·Wo − tn·Wd2
    float accB[4][8] = {};  // f·Wd1
    for (int d = 0; d < DIM; d += 4) {
        f32x4 fr[4], tr[4];
#pragma unroll
        for (int rr = 0; rr < 4; ++rr) {
            fr[rr] = *reinterpret_cast<const f32x4*>(&fs[rt * 4 + rr][d]);
            tr[rr] = *reinterpret_cast<const f32x4*>(&tn[rt * 4 + rr][d]);
        }
#pragma unroll
        for (int hh = 0; hh < 8; ++hh) {
            int h = ht * 8 + hh;
            f32x4 wo = *reinterpret_cast<const f32x4*>(Wo + (size_t)h * DIM + d);
            f32x4 w1 = *reinterpret_cast<const f32x4*>(Wd + (size_t)h * 2 * DIM + d);
            f32x4 w2 = *reinterpret_cast<const f32x4*>(Wd + (size_t)h * 2 * DIM + DIM + d);
#pragma unroll
            for (int rr = 0; rr < 4; ++rr)
#pragma unroll
                for (int c = 0; c < 4; ++c) {
                    accM[rr][hh] += fr[rr][c] * wo[c] - tr[rr][c] * w2[c];
                    accB[rr][hh] += fr[rr][c] * w1[c];
                }
        }
    }
    f32x4 bo0 = *reinterpret_cast<const f32x4*>(bo + ht * 8);
    f32x4 bo1 = *reinterpret_cast<const f32x4*>(bo + ht * 8 + 4);
    f32x4 bd0 = *reinterpret_cast<const f32x4*>(bd + ht * 8);
    f32x4 bd1 = *reinterpret_cast<const f32x4*>(bd + ht * 8 + 4);
#pragma unroll
    for (int rr = 0; rr < 4; ++rr) {
        int i = i0 + rt * 4 + rr;
        float m = mrow[rt * 4 + rr];
        f32x4 v0, v1;
#pragma unroll
        for (int c = 0; c < 4; ++c) {
            v0[c] = tanhf(accM[rr][c]     - m * accB[rr][c]     + bo0[c] - bd0[c]);
            v1[c] = tanhf(accM[rr][c + 4] - m * accB[rr][c + 4] + bo1[c] - bd1[c]);
        }
        float* o = out + (size_t)i * HOUT + ht * 8;
        *reinterpret_cast<f32x4*>(o) = v0;
        *reinterpret_cast<f32x4*>(o + 4) = v1;
        float* o2 = o + (size_t)NROW * HOUT;
        *reinterpret_cast<f32x4*>(o2) = v0;
        *reinterpret_cast<f32x4*>(o2 + 4) = v1;
    }
}

extern "C" void kernel_launch(void* const* d_in, const int* in_sizes, int n_in,
                              void* d_out, int out_size, void* d_ws, size_t ws_size,
                              hipStream_t stream) {
    const float* feat = (const float*)d_in[0];
    const int*   adj  = (const int*)d_in[1];
    const float* Wd   = (const float*)d_in[2];
    const float* bd   = (const float*)d_in[3];
    const float* Wo   = (const float*)d_in[4];
    const float* bo   = (const float*)d_in[5];
    float* out = (float*)d_out;
    char* ws = (char*)d_ws;
    short* fT   = (short*)ws;                              //  4 MB: [128][16384] bf16
    float* part = (float*)(ws + (size_t)4  * 1024 * 1024); // 33.5 MB: [4][16384][128] f32
    float* deg  = (float*)(ws + (size_t)40 * 1024 * 1024); // 64 KB
    k_transpose<<<256, 256, 0, stream>>>(feat, fT, deg);
    k_gemm     <<<512, 256, 0, stream>>>(adj, fT, part, deg);
    k_epilogue <<<512, 256, 0, stream>>>(feat, part, deg, Wd, bd, Wo, bo, out);
}